// Round 21
// baseline (281.707 us; speedup 1.0000x reference)
//
#include <hip/hip_runtime.h>
#include <hip/hip_bf16.h>

// PolicyNet inference: 4 pyramid levels, each: GN(8g)->ReLU->Conv1x1(256->256)
// ->GN->ReLU->Conv1x1(256->1); concat logits [8,21760]; top-100 indices.
// d_out is FLOAT32: [8*100 sample_ids as floats][8*21760 logits as f32].
//
// GEMM on MFMA (16x16x32 bf16) hi/lo split: W*X ~= Whi*Xhi + Whi*Xlo + Wlo*Xhi.
// Pass 1 (r18 structure, MODE 1): persistent grid=256, dbuf LDS, reg-prefetch;
//   ALSO stores each staged hi/lo X tile to Xbf in pass-2-native fragment
//   order (lane-consecutive 16B stores = coalesced 1KB/instr).
// Pass 2 (k_gemm2): 2720 blocks, NO staging/LDS-X/barriers in K-loop; B-frags
//   loaded directly from Xbf; fused GN2+W2 epilogue. Bit-identical logits.
// Fallback (ws too small): r18's 2-pass recompute path (MODE 0 + MODE 2).

#define B_ 8
#define C_ 256
#define G_ 8
#define P_ 21760
#define EPSV 1e-5f
#define XSS 264                 // ushorts per pixel row (528B)
#define XHALF (64 * XSS)        // one hi (or lo) plane
#define XBUF (2 * XHALF)        // hi+lo plane pair per buffer
#define NTILES 2720             // 340 tiles x 8 batches

typedef __attribute__((ext_vector_type(4))) float floatx4;
typedef __attribute__((ext_vector_type(8))) __bf16 bf16x8;

__device__ __constant__ int kL[4]   = {16384, 4096, 1024, 256};
__device__ __constant__ int kOFF[4] = {0, 16384, 20480, 21504};

__device__ __forceinline__ void bf16split(float v, ushort& hi, ushort& lo) {
    __hip_bfloat16 h = __float2bfloat16(v);
    float hf = __bfloat162float(h);
    __hip_bfloat16 l = __float2bfloat16(v - hf);
    hi = *reinterpret_cast<ushort*>(&h);
    lo = *reinterpret_cast<ushort*>(&l);
}

// order-preserving f32 -> u32
__device__ __forceinline__ unsigned fkey(float f) {
    unsigned u = __float_as_uint(f);
    if (u == 0x80000000u) u = 0u;
    return (u & 0x80000000u) ? ~u : (u | 0x80000000u);
}

// ---------------- GN1 partial stats (+ W split piggyback) ----------------
__global__ __launch_bounds__(256) void k_stats1(const float* __restrict__ x0,
                                                const float* __restrict__ x1,
                                                const float* __restrict__ x2,
                                                const float* __restrict__ x3,
                                                const float* __restrict__ W1,
                                                ushort* __restrict__ Whi,
                                                ushort* __restrict__ Wlo,
                                                float* __restrict__ part1) {
    int chunk = blockIdx.x, b = blockIdx.y, t = threadIdx.x;
    int flat = b * 85 + chunk;
    if (flat < 256) {
        int i = flat * 256 + t;
        ushort h, l;
        bf16split(W1[i], h, l);
        Whi[i] = h; Wlo[i] = l;
    }
    int lvl = chunk < 64 ? 0 : (chunk < 80 ? 1 : (chunk < 84 ? 2 : 3));
    const float* xp = lvl == 0 ? x0 : lvl == 1 ? x1 : lvl == 2 ? x2 : x3;
    int Ll = kL[lvl];
    int w = t >> 6, lane = t & 63;
    int l = chunk * 256 - kOFF[lvl] + lane * 4;
    __shared__ float redS[32], redQ[32];
    for (int g = 0; g < 8; ++g) {
        float s = 0.f, q = 0.f;
#pragma unroll
        for (int it = 0; it < 8; ++it) {
            int c = g * 32 + w * 8 + it;
            floatx4 v = *reinterpret_cast<const floatx4*>(xp + (b * 256 + c) * Ll + l);
            s += v.x + v.y + v.z + v.w;
            q += v.x * v.x + v.y * v.y + v.z * v.z + v.w * v.w;
        }
        for (int off = 32; off; off >>= 1) {
            s += __shfl_xor(s, off, 64);
            q += __shfl_xor(q, off, 64);
        }
        if (lane == 0) { redS[g * 4 + w] = s; redQ[g * 4 + w] = q; }
    }
    __syncthreads();
    if (t < 8) {
        float S = redS[t * 4] + redS[t * 4 + 1] + redS[t * 4 + 2] + redS[t * 4 + 3];
        float Q = redQ[t * 4] + redQ[t * 4 + 1] + redQ[t * 4 + 2] + redQ[t * 4 + 3];
        part1[((b * 85 + chunk) * 8 + t) * 2]     = S;
        part1[((b * 85 + chunk) * 8 + t) * 2 + 1] = Q;
    }
}

// ---------------- finalize -> alpha/beta (256 blocks x 64 lanes) ----------------
__global__ __launch_bounds__(64) void k_finalize(const float* __restrict__ part, int div,
                                                 const float* __restrict__ gsc,
                                                 const float* __restrict__ gbi,
                                                 float* __restrict__ ab) {
    int blk = blockIdx.x;                 // b*32 + lvl*8 + g
    int b = blk >> 5, lvl = (blk >> 3) & 3, g = blk & 7;
    int lane = threadIdx.x;
    int start = kOFF[lvl] / div, cnt = kL[lvl] / div, nch = P_ / div;
    float s = 0.f, q = 0.f;
    for (int m = lane; m < cnt; m += 64) {
        const float* p = part + ((b * nch + start + m) * 8 + g) * 2;
        s += p[0]; q += p[1];
    }
    for (int off = 32; off; off >>= 1) {
        s += __shfl_xor(s, off, 64);
        q += __shfl_xor(q, off, 64);
    }
    float N = 32.f * (float)kL[lvl];
    float mean = s / N;
    float var = q / N - mean * mean;
    float inv = rsqrtf(var + EPSV);
    if (lane < 32) {
        int c = g * 32 + lane;
        float a = inv * gsc[c];
        ab[(b * 4 + lvl) * 256 + c] = a;
        ab[8192 + (b * 4 + lvl) * 256 + c] = gbi[c] - mean * a;
    }
}

// ---------------- Pass-1 MFMA GEMM: persistent, dbuf LDS, W-frags hoisted ----------------
// MODE 0: GN2 partial stats only (fallback).
// MODE 1: stats + store staged X tiles to Xbf (fragment-native order).
// MODE 2: fused GN2+W2 -> logits (fallback pass 2).
template <int MODE>
__global__ __launch_bounds__(512) void k_gemm(
    const float* __restrict__ x0, const float* __restrict__ x1,
    const float* __restrict__ x2, const float* __restrict__ x3,
    const ushort* __restrict__ Whi, const ushort* __restrict__ Wlo,
    const float* __restrict__ ab1, const float* __restrict__ b1,
    float* __restrict__ part2, const float* __restrict__ ab2,
    const float* __restrict__ W2, const float* __restrict__ b2,
    ushort* __restrict__ Xbf, float* __restrict__ outF) {
    __shared__ ushort Xs[2 * XBUF];      // 2 buffers x (hi|lo) x [64][264]
    __shared__ float sRed[32 * 64];      // MODE2 reduce scratch

    int t = threadIdx.x;
    int wv = t >> 6, lane = t & 63, lr = lane & 15, kg = lane >> 4;
    int ob = wv * 32;              // 32 output rows per wave
    int px = lane;                 // staging pixel
    int cb = wv * 32;              // staging channel base

    // ---- hoist ALL W fragments (invariant across tiles) ----
    bf16x8 awh[8][2], awl[8][2];
#pragma unroll
    for (int kk = 0; kk < 8; ++kk)
#pragma unroll
        for (int mi = 0; mi < 2; ++mi) {
            int o = ob + mi * 16 + lr;
            awh[kk][mi] = *reinterpret_cast<const bf16x8*>(Whi + o * 256 + kk * 32 + 8 * kg);
            awl[kk][mi] = *reinterpret_cast<const bf16x8*>(Wlo + o * 256 + kk * 32 + 8 * kg);
        }

    // ---- prologue: stage tile0 into buf0 ----
    int tid0 = blockIdx.x;
    {
        int b = tid0 / 340, tile = tid0 % 340;
        int lvl = tile < 256 ? 0 : (tile < 320 ? 1 : (tile < 336 ? 2 : 3));
        const float* xp = lvl == 0 ? x0 : lvl == 1 ? x1 : lvl == 2 ? x2 : x3;
        const float* a1p  = ab1 + (b * 4 + lvl) * 256;
        const float* be1p = a1p + 8192;
        const float* xc = xp + (b * 256 + cb) * kL[lvl] + (tile * 64 - kOFF[lvl]) + px;
        int Ll = kL[lvl];
        float xv[32];
#pragma unroll
        for (int u = 0; u < 32; ++u) xv[u] = xc[u * Ll];
#pragma unroll
        for (int q8 = 0; q8 < 4; ++q8) {
            alignas(16) ushort hs[8], ls[8];
#pragma unroll
            for (int u = 0; u < 8; ++u) {
                int c = cb + q8 * 8 + u;
                bf16split(fmaxf(fmaf(a1p[c], xv[q8 * 8 + u], be1p[c]), 0.f), hs[u], ls[u]);
            }
            *reinterpret_cast<uint4*>(&Xs[px * XSS + cb + q8 * 8]) =
                *reinterpret_cast<const uint4*>(hs);
            *reinterpret_cast<uint4*>(&Xs[XHALF + px * XSS + cb + q8 * 8]) =
                *reinterpret_cast<const uint4*>(ls);
            if (MODE == 1) {
                ushort* xb = Xbf + (size_t)tid0 * 32768 + ((wv * 4 + q8) * 64 + lane) * 8;
                *reinterpret_cast<uint4*>(xb)         = *reinterpret_cast<const uint4*>(hs);
                *reinterpret_cast<uint4*>(xb + 16384) = *reinterpret_cast<const uint4*>(ls);
            }
        }
    }

    int cur = 0;
    for (int tid = tid0; tid < NTILES; tid += 256) {
        int b = tid / 340, tile = tid % 340;
        int lvl = tile < 256 ? 0 : (tile < 320 ? 1 : (tile < 336 ? 2 : 3));

        // ---- issue next tile's loads EARLY (land under this tile's epoch) ----
        int ntid = tid + 256;
        bool have = ntid < NTILES;
        float nxv[32];
        const float *na1p = nullptr, *nbe1p = nullptr;
        if (have) {
            int nb = ntid / 340, ntile = ntid % 340;
            int nlvl = ntile < 256 ? 0 : (ntile < 320 ? 1 : (ntile < 336 ? 2 : 3));
            const float* nxp = nlvl == 0 ? x0 : nlvl == 1 ? x1 : nlvl == 2 ? x2 : x3;
            na1p  = ab1 + (nb * 4 + nlvl) * 256;
            nbe1p = na1p + 8192;
            int nLl = kL[nlvl];
            const float* nxc = nxp + (nb * 256 + cb) * nLl + (ntile * 64 - kOFF[nlvl]) + px;
#pragma unroll
            for (int u = 0; u < 32; ++u) nxv[u] = nxc[u * nLl];
        }

        __syncthreads();   // buf[cur] staged & visible; prev readers of buf[cur^1] done

        // ---- MFMA epoch on buf[cur] (pure LDS + MFMA; W in regs) ----
        const ushort* XH = Xs + cur * XBUF;
        const ushort* XL = XH + XHALF;

        floatx4 acc[2][4];
#pragma unroll
        for (int mi = 0; mi < 2; ++mi)
#pragma unroll
            for (int ni = 0; ni < 4; ++ni) acc[mi][ni] = (floatx4){0.f, 0.f, 0.f, 0.f};

#pragma unroll
        for (int kk = 0; kk < 8; ++kk) {
            bf16x8 bh[4], bl[4];
#pragma unroll
            for (int ni = 0; ni < 4; ++ni) {
                int p = ni * 16 + lr;
                bh[ni] = *reinterpret_cast<const bf16x8*>(&XH[p * XSS + kk * 32 + 8 * kg]);
                bl[ni] = *reinterpret_cast<const bf16x8*>(&XL[p * XSS + kk * 32 + 8 * kg]);
            }
#pragma unroll
            for (int mi = 0; mi < 2; ++mi)
#pragma unroll
                for (int ni = 0; ni < 4; ++ni) {
                    acc[mi][ni] = __builtin_amdgcn_mfma_f32_16x16x32_bf16(awh[kk][mi], bh[ni], acc[mi][ni], 0, 0, 0);
                    acc[mi][ni] = __builtin_amdgcn_mfma_f32_16x16x32_bf16(awh[kk][mi], bl[ni], acc[mi][ni], 0, 0, 0);
                    acc[mi][ni] = __builtin_amdgcn_mfma_f32_16x16x32_bf16(awl[kk][mi], bh[ni], acc[mi][ni], 0, 0, 0);
                }
        }

        // bias: acc = Y   (thread rows: o = ob + mi*16 + 4*kg + r)
        floatx4 b1f[2];
#pragma unroll
        for (int mi = 0; mi < 2; ++mi)
            b1f[mi] = *reinterpret_cast<const floatx4*>(b1 + ob + mi * 16 + 4 * kg);
#pragma unroll
        for (int mi = 0; mi < 2; ++mi)
#pragma unroll
            for (int ni = 0; ni < 4; ++ni)
#pragma unroll
                for (int r = 0; r < 4; ++r)
                    acc[mi][ni][r] += b1f[mi][r];

        if (MODE == 0 || MODE == 1) {
            // wave wv covers o in [wv*32, wv*32+32) == GN2 group wv exactly
            float s = 0.f, q = 0.f;
#pragma unroll
            for (int mi = 0; mi < 2; ++mi)
#pragma unroll
                for (int ni = 0; ni < 4; ++ni)
#pragma unroll
                    for (int r = 0; r < 4; ++r) {
                        float yv = acc[mi][ni][r];
                        s += yv; q += yv * yv;
                    }
            for (int off = 32; off; off >>= 1) {
                s += __shfl_xor(s, off, 64);
                q += __shfl_xor(q, off, 64);
            }
            if (lane == 0) {
                int base = (b * 340 + tile) * 8;
                part2[(base + wv) * 2]     = s;
                part2[(base + wv) * 2 + 1] = q;
            }
        } else {  // MODE 2: fused GN2 -> ReLU -> W2 dot
            const float* a2p  = ab2 + (b * 4 + lvl) * 256;
            const float* be2p = a2p + 8192;
            float sj[4] = {0.f, 0.f, 0.f, 0.f};
#pragma unroll
            for (int mi = 0; mi < 2; ++mi) {
                int o4 = ob + mi * 16 + 4 * kg;
                floatx4 a2f  = *reinterpret_cast<const floatx4*>(a2p + o4);
                floatx4 be2f = *reinterpret_cast<const floatx4*>(be2p + o4);
                floatx4 w2f  = *reinterpret_cast<const floatx4*>(W2 + o4);
#pragma unroll
                for (int r = 0; r < 4; ++r) {
                    float a2 = a2f[r], be2 = be2f[r], w2 = w2f[r];
#pragma unroll
                    for (int ni = 0; ni < 4; ++ni) {
                        float h = fmaxf(fmaf(a2, acc[mi][ni][r], be2), 0.f);
                        sj[ni] = fmaf(w2, h, sj[ni]);
                    }
                }
            }
#pragma unroll
            for (int ni = 0; ni < 4; ++ni)
                sRed[(wv * 4 + kg) * 64 + ni * 16 + lr] = sj[ni];
            __syncthreads();
            if (t < 64) {
                float lg = b2[0];
#pragma unroll
                for (int m = 0; m < 32; ++m) lg += sRed[m * 64 + t];
                outF[800 + b * P_ + tile * 64 + t] = lg;
            }
        }

        // ---- split + write NEXT tile into buf[cur^1] (loads already in flight) ----
        if (have) {
            ushort* DH = Xs + (cur ^ 1) * XBUF;
            ushort* DL = DH + XHALF;
#pragma unroll
            for (int q8 = 0; q8 < 4; ++q8) {
                alignas(16) ushort hs[8], ls[8];
#pragma unroll
                for (int u = 0; u < 8; ++u) {
                    int c = cb + q8 * 8 + u;
                    bf16split(fmaxf(fmaf(na1p[c], nxv[q8 * 8 + u], nbe1p[c]), 0.f), hs[u], ls[u]);
                }
                *reinterpret_cast<uint4*>(&DH[px * XSS + cb + q8 * 8]) =
                    *reinterpret_cast<const uint4*>(hs);
                *reinterpret_cast<uint4*>(&DL[px * XSS + cb + q8 * 8]) =
                    *reinterpret_cast<const uint4*>(ls);
                if (MODE == 1) {
                    ushort* xb = Xbf + (size_t)ntid * 32768 + ((wv * 4 + q8) * 64 + lane) * 8;
                    *reinterpret_cast<uint4*>(xb)         = *reinterpret_cast<const uint4*>(hs);
                    *reinterpret_cast<uint4*>(xb + 16384) = *reinterpret_cast<const uint4*>(ls);
                }
            }
        }
        cur ^= 1;
    }
}

// ---------------- Pass 2: B-frags straight from Xbf; no staging, no K-loop barriers ----------------
__global__ __launch_bounds__(512) void k_gemm2(
    const ushort* __restrict__ Xbf,
    const ushort* __restrict__ Whi, const ushort* __restrict__ Wlo,
    const float* __restrict__ b1, const float* __restrict__ ab2,
    const float* __restrict__ W2, const float* __restrict__ b2,
    float* __restrict__ outF) {
    __shared__ float sRed[32 * 64];
    int tid = blockIdx.x;                 // 0..2719
    int b = tid / 340, tile = tid % 340;
    int t = threadIdx.x;
    int wv = t >> 6, lane = t & 63, lr = lane & 15, kg = lane >> 4;
    int ob = wv * 32;
    int lvl = tile < 256 ? 0 : (tile < 320 ? 1 : (tile < 336 ? 2 : 3));
    const ushort* xb = Xbf + (size_t)tid * 32768;

    floatx4 acc[2][4];
#pragma unroll
    for (int mi = 0; mi < 2; ++mi)
#pragma unroll
        for (int ni = 0; ni < 4; ++ni) acc[mi][ni] = (floatx4){0.f, 0.f, 0.f, 0.f};

#pragma unroll
    for (int kk = 0; kk < 8; ++kk) {
        bf16x8 ah[2], al[2], bh[4], bl[4];
#pragma unroll
        for (int mi = 0; mi < 2; ++mi) {
            int o = ob + mi * 16 + lr;
            ah[mi] = *reinterpret_cast<const bf16x8*>(Whi + o * 256 + kk * 32 + 8 * kg);
            al[mi] = *reinterpret_cast<const bf16x8*>(Wlo + o * 256 + kk * 32 + 8 * kg);
        }
#pragma unroll
        for (int ni = 0; ni < 4; ++ni) {
            int p = ni * 16 + lr;
            const ushort* q = xb + ((kk * 4 + kg) * 64 + p) * 8;
            bh[ni] = *reinterpret_cast<const bf16x8*>(q);
            bl[ni] = *reinterpret_cast<const bf16x8*>(q + 16384);
        }
#pragma unroll
        for (int mi = 0; mi < 2; ++mi)
#pragma unroll
            for (int ni = 0; ni < 4; ++ni) {
                acc[mi][ni] = __builtin_amdgcn_mfma_f32_16x16x32_bf16(ah[mi], bh[ni], acc[mi][ni], 0, 0, 0);
                acc[mi][ni] = __builtin_amdgcn_mfma_f32_16x16x32_bf16(ah[mi], bl[ni], acc[mi][ni], 0, 0, 0);
                acc[mi][ni] = __builtin_amdgcn_mfma_f32_16x16x32_bf16(al[mi], bh[ni], acc[mi][ni], 0, 0, 0);
            }
    }

    floatx4 b1f[2];
#pragma unroll
    for (int mi = 0; mi < 2; ++mi)
        b1f[mi] = *reinterpret_cast<const floatx4*>(b1 + ob + mi * 16 + 4 * kg);
#pragma unroll
    for (int mi = 0; mi < 2; ++mi)
#pragma unroll
        for (int ni = 0; ni < 4; ++ni)
#pragma unroll
            for (int r = 0; r < 4; ++r)
                acc[mi][ni][r] += b1f[mi][r];

    const float* a2p  = ab2 + (b * 4 + lvl) * 256;
    const float* be2p = a2p + 8192;
    float sj[4] = {0.f, 0.f, 0.f, 0.f};
#pragma unroll
    for (int mi = 0; mi < 2; ++mi) {
        int o4 = ob + mi * 16 + 4 * kg;
        floatx4 a2f  = *reinterpret_cast<const floatx4*>(a2p + o4);
        floatx4 be2f = *reinterpret_cast<const floatx4*>(be2p + o4);
        floatx4 w2f  = *reinterpret_cast<const floatx4*>(W2 + o4);
#pragma unroll
        for (int r = 0; r < 4; ++r) {
            float a2 = a2f[r], be2 = be2f[r], w2 = w2f[r];
#pragma unroll
            for (int ni = 0; ni < 4; ++ni) {
                float h = fmaxf(fmaf(a2, acc[mi][ni][r], be2), 0.f);
                sj[ni] = fmaf(w2, h, sj[ni]);
            }
        }
    }
#pragma unroll
    for (int ni = 0; ni < 4; ++ni)
        sRed[(wv * 4 + kg) * 64 + ni * 16 + lr] = sj[ni];
    __syncthreads();
    if (t < 64) {
        float lg = b2[0];
#pragma unroll
        for (int m = 0; m < 32; ++m) lg += sRed[m * 64 + t];
        outF[800 + b * P_ + tile * 64 + t] = lg;
    }
}

// ---------------- exact top-100 per batch: radix select + bitonic sort ----------------
__global__ __launch_bounds__(1024) void k_topk(const float* __restrict__ outF,
                                               float* __restrict__ outIds) {
    int b = blockIdx.x, t = threadIdx.x;
    int lane = t & 63;
    __shared__ unsigned hist[256];
    __shared__ unsigned scan[256];
    __shared__ unsigned wsum[4];
    __shared__ unsigned s_pref, s_K, s_iref, s_K2;
    __shared__ unsigned s_cnt;
    __shared__ unsigned long long cand[128];

    const float* src = outF + 800 + b * P_;
    unsigned key[22];
#pragma unroll
    for (int m = 0; m < 21; ++m) key[m] = fkey(src[t + m * 1024]);
    key[21] = (t < 256) ? fkey(src[t + 21504]) : 0u;
    bool has22 = (t < 256);

    if (t == 0) { s_K = 100; s_pref = 0; }

#pragma unroll
    for (int p = 0; p < 4; ++p) {
        int shift = 24 - 8 * p;
        for (int i = t; i < 256; i += 1024) hist[i] = 0;
        __syncthreads();
        unsigned pref = s_pref;
#pragma unroll
        for (int m = 0; m < 22; ++m) {
            if (m < 21 || has22) {
                unsigned u = key[m];
                if (p == 0 || (u >> (shift + 8)) == pref)
                    atomicAdd(&hist[(u >> shift) & 255], 1u);
            }
        }
        __syncthreads();
        unsigned inc = 0, hv = 0;
        if (t < 256) {
            hv = hist[t];
            inc = hv;
#pragma unroll
            for (int off = 1; off < 64; off <<= 1) {
                unsigned u = __shfl_up(inc, off, 64);
                if (lane >= off) inc += u;
            }
            if (lane == 63) wsum[t >> 6] = inc;
        }
        __syncthreads();
        if (t < 256) {
            unsigned base = 0;
#pragma unroll
            for (int w = 0; w < 4; ++w) if (w < (t >> 6)) base += wsum[w];
            unsigned P = base + inc;
            unsigned T4 = wsum[0] + wsum[1] + wsum[2] + wsum[3];
            scan[t] = T4 - P + hv;   // inclusive suffix sum
        }
        __syncthreads();
        unsigned K = s_K;
        if (t < 256) {
            unsigned above = (t == 255) ? 0u : scan[t + 1];
            if (scan[t] >= K && above < K) {
                s_pref = (s_pref << 8) | (unsigned)t;
                s_K = K - above;
            }
        }
        __syncthreads();
    }
    unsigned T = s_pref;
    if (t == 0) { s_K2 = s_K; s_iref = 0; }
    __syncthreads();

#pragma unroll
    for (int p = 0; p < 2; ++p) {
        int shift = 8 - 8 * p;
        for (int i = t; i < 256; i += 1024) hist[i] = 0;
        __syncthreads();
        unsigned iref = s_iref;
#pragma unroll
        for (int m = 0; m < 22; ++m) {
            if (m < 21 || has22) {
                unsigned u = key[m];
                unsigned idx = (unsigned)(t + m * 1024);
                if (u == T && (p == 0 || (idx >> 8) == iref))
                    atomicAdd(&hist[(idx >> shift) & 255], 1u);
            }
        }
        __syncthreads();
        unsigned inc = 0;
        if (t < 256) {
            inc = hist[t];
#pragma unroll
            for (int off = 1; off < 64; off <<= 1) {
                unsigned u = __shfl_up(inc, off, 64);
                if (lane >= off) inc += u;
            }
            if (lane == 63) wsum[t >> 6] = inc;
        }
        __syncthreads();
        if (t < 256) {
            unsigned base = 0;
#pragma unroll
            for (int w = 0; w < 4; ++w) if (w < (t >> 6)) base += wsum[w];
            scan[t] = base + inc;    // inclusive prefix sum
        }
        __syncthreads();
        unsigned K2 = s_K2;
        if (t < 256) {
            unsigned below = (t == 0) ? 0u : scan[t - 1];
            if (scan[t] >= K2 && below < K2) {
                s_iref = (s_iref << 8) | (unsigned)t;
                s_K2 = K2 - below;
            }
        }
        __syncthreads();
    }
    unsigned Ti = s_iref;

    if (t == 0) s_cnt = 0;
    if (t < 128) cand[t] = 0ull;
    __syncthreads();
#pragma unroll
    for (int m = 0; m < 22; ++m) {
        if (m < 21 || has22) {
            unsigned u = key[m];
            unsigned idx = (unsigned)(t + m * 1024);
            if (u > T || (u == T && idx <= Ti)) {
                unsigned p = atomicAdd(&s_cnt, 1u);
                if (p < 128)
                    cand[p] = ((unsigned long long)u << 32) | (unsigned long long)(0xFFFFFFFFu - idx);
            }
        }
    }
    __syncthreads();

    for (unsigned k = 2; k <= 128; k <<= 1) {
        for (unsigned j = k >> 1; j > 0; j >>= 1) {
            if (t < 128) {
                unsigned i = t, ixj = i ^ j;
                if (ixj > i) {
                    unsigned long long a = cand[i], c = cand[ixj];
                    bool desc = ((i & k) == 0);
                    if ((a < c) == desc) { cand[i] = c; cand[ixj] = a; }
                }
            }
            __syncthreads();
        }
    }
    if (t < 100) {
        unsigned idx = 0xFFFFFFFFu - (unsigned)(cand[t] & 0xFFFFFFFFull);
        outIds[b * 100 + t] = (float)idx;
    }
}

extern "C" void kernel_launch(void* const* d_in, const int* in_sizes, int n_in,
                              void* d_out, int out_size, void* d_ws, size_t ws_size,
                              hipStream_t stream) {
    const float* x0  = (const float*)d_in[0];
    const float* x1  = (const float*)d_in[1];
    const float* x2  = (const float*)d_in[2];
    const float* x3  = (const float*)d_in[3];
    const float* g1s = (const float*)d_in[4];
    const float* g1b = (const float*)d_in[5];
    const float* W1  = (const float*)d_in[6];
    const float* b1  = (const float*)d_in[7];
    const float* g2s = (const float*)d_in[8];
    const float* g2b = (const float*)d_in[9];
    const float* W2  = (const float*)d_in[10];
    const float* b2  = (const float*)d_in[11];
    float* outF = (float*)d_out;
    float* ws = (float*)d_ws;

    // ws layout (floats)
    float*  ab1   = ws;                     // 16384
    float*  ab2   = ws + 16384;             // 16384
    float*  U     = ws + 32768;             // 43520 (part1/part2)
    float*  part1 = U;
    float*  part2 = U;
    ushort* Whi   = (ushort*)(ws + 76288);  // 65536 ushorts
    ushort* Wlo   = (ushort*)(ws + 109056); // 65536 ushorts
    ushort* Xbf   = (ushort*)(ws + 141824); // 89,128,960 ushorts (optional)
    bool useX = ws_size >= (size_t)(141824 + 44564480) * 4;

    k_stats1<<<dim3(85, 8), dim3(256), 0, stream>>>(x0, x1, x2, x3, W1, Whi, Wlo, part1);
    k_finalize<<<dim3(256), dim3(64), 0, stream>>>(part1, 256, g1s, g1b, ab1);
    if (useX) {
        k_gemm<1><<<dim3(256), dim3(512), 0, stream>>>(x0, x1, x2, x3, Whi, Wlo, ab1, b1,
                                                       part2, ab2, W2, b2, Xbf, outF);
        k_finalize<<<dim3(256), dim3(64), 0, stream>>>(part2, 64, g2s, g2b, ab2);
        k_gemm2<<<dim3(NTILES), dim3(512), 0, stream>>>(Xbf, Whi, Wlo, b1, ab2, W2, b2, outF);
    } else {
        k_gemm<0><<<dim3(256), dim3(512), 0, stream>>>(x0, x1, x2, x3, Whi, Wlo, ab1, b1,
                                                       part2, ab2, W2, b2, Xbf, outF);
        k_finalize<<<dim3(256), dim3(64), 0, stream>>>(part2, 64, g2s, g2b, ab2);
        k_gemm<2><<<dim3(256), dim3(512), 0, stream>>>(x0, x1, x2, x3, Whi, Wlo, ab1, b1,
                                                       part2, ab2, W2, b2, Xbf, outF);
    }
    k_topk<<<dim3(8), dim3(1024), 0, stream>>>(outF, outF);
}

// Round 22
// 199.053 us; speedup vs baseline: 1.4152x; 1.4152x over previous
//
#include <hip/hip_runtime.h>
#include <hip/hip_bf16.h>

// PolicyNet inference: 4 pyramid levels, each: GN(8g)->ReLU->Conv1x1(256->256)
// ->GN->ReLU->Conv1x1(256->1); concat logits [8,21760]; top-100 indices.
// d_out is FLOAT32: [8*100 sample_ids as floats][8*21760 logits as f32].
//
// FINAL build — exact r18/r20 configuration (best measured: 199.5us, x2 repro):
//  - k_gemm: persistent grid=256, 512 thr = 8 waves x 32 rows, N=64 px tiles,
//    double-buffered full-K LDS, register-prefetch pipeline, W-frags hoisted,
//    plain __launch_bounds__(512). GEMM 84-85us/pass.
//  - k_stats1: GN1 stats + W hi/lo split folded in.
//  - k_finalize: 256 blocks x 64 lanes (parallel).
//  - k_topk: exact radix select (value, then index tie-break), shuffle scans.
// Search ledger (915 -> 199.5us): MFMA hi/lo split 915->553; radix topk ->365;
// conflict-free staging; persistent+prefetch ->283; parallel finalize ->199.5.
// Dead ends (measured): storeY & Xbf handoff (178MB intermediates lose to
// recompute); min-waves clauses (spill); single-buf 2-blk/CU (no coreside);
// barrier reorder, W reg-dbuf, M/N retiling (all null at the 2-barrier
// structure ceiling: MfmaUtil ~32%).

#define B_ 8
#define C_ 256
#define G_ 8
#define P_ 21760
#define EPSV 1e-5f
#define XSS 264                 // ushorts per pixel row (528B)
#define XHALF (64 * XSS)        // one hi (or lo) plane
#define XBUF (2 * XHALF)        // hi+lo plane pair per buffer
#define NTILES 2720             // 340 tiles x 8 batches

typedef __attribute__((ext_vector_type(4))) float floatx4;
typedef __attribute__((ext_vector_type(8))) __bf16 bf16x8;

__device__ __constant__ int kL[4]   = {16384, 4096, 1024, 256};
__device__ __constant__ int kOFF[4] = {0, 16384, 20480, 21504};

__device__ __forceinline__ void bf16split(float v, ushort& hi, ushort& lo) {
    __hip_bfloat16 h = __float2bfloat16(v);
    float hf = __bfloat162float(h);
    __hip_bfloat16 l = __float2bfloat16(v - hf);
    hi = *reinterpret_cast<ushort*>(&h);
    lo = *reinterpret_cast<ushort*>(&l);
}

// order-preserving f32 -> u32
__device__ __forceinline__ unsigned fkey(float f) {
    unsigned u = __float_as_uint(f);
    if (u == 0x80000000u) u = 0u;
    return (u & 0x80000000u) ? ~u : (u | 0x80000000u);
}

// ---------------- GN1 partial stats (+ W split piggyback) ----------------
__global__ __launch_bounds__(256) void k_stats1(const float* __restrict__ x0,
                                                const float* __restrict__ x1,
                                                const float* __restrict__ x2,
                                                const float* __restrict__ x3,
                                                const float* __restrict__ W1,
                                                ushort* __restrict__ Whi,
                                                ushort* __restrict__ Wlo,
                                                float* __restrict__ part1) {
    int chunk = blockIdx.x, b = blockIdx.y, t = threadIdx.x;
    // piggyback: first 256 flat blocks each split 256 W elements
    int flat = b * 85 + chunk;
    if (flat < 256) {
        int i = flat * 256 + t;
        ushort h, l;
        bf16split(W1[i], h, l);
        Whi[i] = h; Wlo[i] = l;
    }
    int lvl = chunk < 64 ? 0 : (chunk < 80 ? 1 : (chunk < 84 ? 2 : 3));
    const float* xp = lvl == 0 ? x0 : lvl == 1 ? x1 : lvl == 2 ? x2 : x3;
    int Ll = kL[lvl];
    int w = t >> 6, lane = t & 63;
    int l = chunk * 256 - kOFF[lvl] + lane * 4;
    __shared__ float redS[32], redQ[32];
    for (int g = 0; g < 8; ++g) {
        float s = 0.f, q = 0.f;
#pragma unroll
        for (int it = 0; it < 8; ++it) {
            int c = g * 32 + w * 8 + it;
            floatx4 v = *reinterpret_cast<const floatx4*>(xp + (b * 256 + c) * Ll + l);
            s += v.x + v.y + v.z + v.w;
            q += v.x * v.x + v.y * v.y + v.z * v.z + v.w * v.w;
        }
        for (int off = 32; off; off >>= 1) {
            s += __shfl_xor(s, off, 64);
            q += __shfl_xor(q, off, 64);
        }
        if (lane == 0) { redS[g * 4 + w] = s; redQ[g * 4 + w] = q; }
    }
    __syncthreads();
    if (t < 8) {
        float S = redS[t * 4] + redS[t * 4 + 1] + redS[t * 4 + 2] + redS[t * 4 + 3];
        float Q = redQ[t * 4] + redQ[t * 4 + 1] + redQ[t * 4 + 2] + redQ[t * 4 + 3];
        part1[((b * 85 + chunk) * 8 + t) * 2]     = S;
        part1[((b * 85 + chunk) * 8 + t) * 2 + 1] = Q;
    }
}

// ---------------- finalize -> alpha/beta (256 blocks x 64 lanes) ----------------
__global__ __launch_bounds__(64) void k_finalize(const float* __restrict__ part, int div,
                                                 const float* __restrict__ gsc,
                                                 const float* __restrict__ gbi,
                                                 float* __restrict__ ab) {
    int blk = blockIdx.x;                 // b*32 + lvl*8 + g
    int b = blk >> 5, lvl = (blk >> 3) & 3, g = blk & 7;
    int lane = threadIdx.x;
    int start = kOFF[lvl] / div, cnt = kL[lvl] / div, nch = P_ / div;
    float s = 0.f, q = 0.f;
    for (int m = lane; m < cnt; m += 64) {
        const float* p = part + ((b * nch + start + m) * 8 + g) * 2;
        s += p[0]; q += p[1];
    }
    for (int off = 32; off; off >>= 1) {
        s += __shfl_xor(s, off, 64);
        q += __shfl_xor(q, off, 64);
    }
    float N = 32.f * (float)kL[lvl];
    float mean = s / N;
    float var = q / N - mean * mean;
    float inv = rsqrtf(var + EPSV);
    if (lane < 32) {
        int c = g * 32 + lane;
        float a = inv * gsc[c];
        ab[(b * 4 + lvl) * 256 + c] = a;
        ab[8192 + (b * 4 + lvl) * 256 + c] = gbi[c] - mean * a;
    }
}

// ---------------- MFMA GEMM: persistent, dbuf LDS, W-frags hoisted in regs ----------------
// MODE 0: GN2 partial stats only.  MODE 2: fused GN2+W2 -> logits.
template <int MODE>
__global__ __launch_bounds__(512) void k_gemm(
    const float* __restrict__ x0, const float* __restrict__ x1,
    const float* __restrict__ x2, const float* __restrict__ x3,
    const ushort* __restrict__ Whi, const ushort* __restrict__ Wlo,
    const float* __restrict__ ab1, const float* __restrict__ b1,
    float* __restrict__ part2, const float* __restrict__ ab2,
    const float* __restrict__ W2, const float* __restrict__ b2,
    float* __restrict__ outF) {
    __shared__ ushort Xs[2 * XBUF];      // 2 buffers x (hi|lo) x [64][264]
    __shared__ float sRed[32 * 64];      // MODE2 reduce scratch

    int t = threadIdx.x;
    int wv = t >> 6, lane = t & 63, lr = lane & 15, kg = lane >> 4;
    int ob = wv * 32;              // 32 output rows per wave
    int px = lane;                 // staging pixel
    int cb = wv * 32;              // staging channel base

    // ---- hoist ALL W fragments (invariant across tiles) ----
    bf16x8 awh[8][2], awl[8][2];
#pragma unroll
    for (int kk = 0; kk < 8; ++kk)
#pragma unroll
        for (int mi = 0; mi < 2; ++mi) {
            int o = ob + mi * 16 + lr;
            awh[kk][mi] = *reinterpret_cast<const bf16x8*>(Whi + o * 256 + kk * 32 + 8 * kg);
            awl[kk][mi] = *reinterpret_cast<const bf16x8*>(Wlo + o * 256 + kk * 32 + 8 * kg);
        }

    // ---- prologue: stage tile0 into buf0 ----
    int tid0 = blockIdx.x;
    {
        int b = tid0 / 340, tile = tid0 % 340;
        int lvl = tile < 256 ? 0 : (tile < 320 ? 1 : (tile < 336 ? 2 : 3));
        const float* xp = lvl == 0 ? x0 : lvl == 1 ? x1 : lvl == 2 ? x2 : x3;
        const float* a1p  = ab1 + (b * 4 + lvl) * 256;
        const float* be1p = a1p + 8192;
        const float* xc = xp + (b * 256 + cb) * kL[lvl] + (tile * 64 - kOFF[lvl]) + px;
        int Ll = kL[lvl];
        float xv[32];
#pragma unroll
        for (int u = 0; u < 32; ++u) xv[u] = xc[u * Ll];
#pragma unroll
        for (int q8 = 0; q8 < 4; ++q8) {
            alignas(16) ushort hs[8], ls[8];
#pragma unroll
            for (int u = 0; u < 8; ++u) {
                int c = cb + q8 * 8 + u;
                bf16split(fmaxf(fmaf(a1p[c], xv[q8 * 8 + u], be1p[c]), 0.f), hs[u], ls[u]);
            }
            *reinterpret_cast<uint4*>(&Xs[px * XSS + cb + q8 * 8]) =
                *reinterpret_cast<const uint4*>(hs);
            *reinterpret_cast<uint4*>(&Xs[XHALF + px * XSS + cb + q8 * 8]) =
                *reinterpret_cast<const uint4*>(ls);
        }
    }

    int cur = 0;
    for (int tid = tid0; tid < NTILES; tid += 256) {
        int b = tid / 340, tile = tid % 340;
        int lvl = tile < 256 ? 0 : (tile < 320 ? 1 : (tile < 336 ? 2 : 3));

        // ---- issue next tile's loads EARLY (land under this tile's epoch) ----
        int ntid = tid + 256;
        bool have = ntid < NTILES;
        float nxv[32];
        const float *na1p = nullptr, *nbe1p = nullptr;
        if (have) {
            int nb = ntid / 340, ntile = ntid % 340;
            int nlvl = ntile < 256 ? 0 : (ntile < 320 ? 1 : (ntile < 336 ? 2 : 3));
            const float* nxp = nlvl == 0 ? x0 : nlvl == 1 ? x1 : nlvl == 2 ? x2 : x3;
            na1p  = ab1 + (nb * 4 + nlvl) * 256;
            nbe1p = na1p + 8192;
            int nLl = kL[nlvl];
            const float* nxc = nxp + (nb * 256 + cb) * nLl + (ntile * 64 - kOFF[nlvl]) + px;
#pragma unroll
            for (int u = 0; u < 32; ++u) nxv[u] = nxc[u * nLl];
        }

        __syncthreads();   // buf[cur] staged & visible; prev readers of buf[cur^1] done

        // ---- MFMA epoch on buf[cur] (pure LDS + MFMA; W in regs) ----
        const ushort* XH = Xs + cur * XBUF;
        const ushort* XL = XH + XHALF;

        floatx4 acc[2][4];
#pragma unroll
        for (int mi = 0; mi < 2; ++mi)
#pragma unroll
            for (int ni = 0; ni < 4; ++ni) acc[mi][ni] = (floatx4){0.f, 0.f, 0.f, 0.f};

#pragma unroll
        for (int kk = 0; kk < 8; ++kk) {
            bf16x8 bh[4], bl[4];
#pragma unroll
            for (int ni = 0; ni < 4; ++ni) {
                int p = ni * 16 + lr;
                bh[ni] = *reinterpret_cast<const bf16x8*>(&XH[p * XSS + kk * 32 + 8 * kg]);
                bl[ni] = *reinterpret_cast<const bf16x8*>(&XL[p * XSS + kk * 32 + 8 * kg]);
            }
#pragma unroll
            for (int mi = 0; mi < 2; ++mi)
#pragma unroll
                for (int ni = 0; ni < 4; ++ni) {
                    acc[mi][ni] = __builtin_amdgcn_mfma_f32_16x16x32_bf16(awh[kk][mi], bh[ni], acc[mi][ni], 0, 0, 0);
                    acc[mi][ni] = __builtin_amdgcn_mfma_f32_16x16x32_bf16(awh[kk][mi], bl[ni], acc[mi][ni], 0, 0, 0);
                    acc[mi][ni] = __builtin_amdgcn_mfma_f32_16x16x32_bf16(awl[kk][mi], bh[ni], acc[mi][ni], 0, 0, 0);
                }
        }

        // bias: acc = Y   (thread rows: o = ob + mi*16 + 4*kg + r)
        floatx4 b1f[2];
#pragma unroll
        for (int mi = 0; mi < 2; ++mi)
            b1f[mi] = *reinterpret_cast<const floatx4*>(b1 + ob + mi * 16 + 4 * kg);
#pragma unroll
        for (int mi = 0; mi < 2; ++mi)
#pragma unroll
            for (int ni = 0; ni < 4; ++ni)
#pragma unroll
                for (int r = 0; r < 4; ++r)
                    acc[mi][ni][r] += b1f[mi][r];

        if (MODE == 0) {
            // wave wv covers o in [wv*32, wv*32+32) == GN2 group wv exactly
            float s = 0.f, q = 0.f;
#pragma unroll
            for (int mi = 0; mi < 2; ++mi)
#pragma unroll
                for (int ni = 0; ni < 4; ++ni)
#pragma unroll
                    for (int r = 0; r < 4; ++r) {
                        float yv = acc[mi][ni][r];
                        s += yv; q += yv * yv;
                    }
            for (int off = 32; off; off >>= 1) {
                s += __shfl_xor(s, off, 64);
                q += __shfl_xor(q, off, 64);
            }
            if (lane == 0) {
                int base = (b * 340 + tile) * 8;
                part2[(base + wv) * 2]     = s;
                part2[(base + wv) * 2 + 1] = q;
            }
        } else {  // MODE 2: fused GN2 -> ReLU -> W2 dot
            const float* a2p  = ab2 + (b * 4 + lvl) * 256;
            const float* be2p = a2p + 8192;
            float sj[4] = {0.f, 0.f, 0.f, 0.f};
#pragma unroll
            for (int mi = 0; mi < 2; ++mi) {
                int o4 = ob + mi * 16 + 4 * kg;
                floatx4 a2f  = *reinterpret_cast<const floatx4*>(a2p + o4);
                floatx4 be2f = *reinterpret_cast<const floatx4*>(be2p + o4);
                floatx4 w2f  = *reinterpret_cast<const floatx4*>(W2 + o4);
#pragma unroll
                for (int r = 0; r < 4; ++r) {
                    float a2 = a2f[r], be2 = be2f[r], w2 = w2f[r];
#pragma unroll
                    for (int ni = 0; ni < 4; ++ni) {
                        float h = fmaxf(fmaf(a2, acc[mi][ni][r], be2), 0.f);
                        sj[ni] = fmaf(w2, h, sj[ni]);
                    }
                }
            }
#pragma unroll
            for (int ni = 0; ni < 4; ++ni)
                sRed[(wv * 4 + kg) * 64 + ni * 16 + lr] = sj[ni];
            __syncthreads();
            if (t < 64) {
                float lg = b2[0];
#pragma unroll
                for (int m = 0; m < 32; ++m) lg += sRed[m * 64 + t];
                outF[800 + b * P_ + tile * 64 + t] = lg;
            }
        }

        // ---- split + write NEXT tile into buf[cur^1] (loads already in flight) ----
        if (have) {
            ushort* DH = Xs + (cur ^ 1) * XBUF;
            ushort* DL = DH + XHALF;
#pragma unroll
            for (int q8 = 0; q8 < 4; ++q8) {
                alignas(16) ushort hs[8], ls[8];
#pragma unroll
                for (int u = 0; u < 8; ++u) {
                    int c = cb + q8 * 8 + u;
                    bf16split(fmaxf(fmaf(na1p[c], nxv[q8 * 8 + u], nbe1p[c]), 0.f), hs[u], ls[u]);
                }
                *reinterpret_cast<uint4*>(&DH[px * XSS + cb + q8 * 8]) =
                    *reinterpret_cast<const uint4*>(hs);
                *reinterpret_cast<uint4*>(&DL[px * XSS + cb + q8 * 8]) =
                    *reinterpret_cast<const uint4*>(ls);
            }
        }
        cur ^= 1;
    }
}

// ---------------- exact top-100 per batch: radix select + bitonic sort ----------------
// Scans via wave shuffles (2 barriers/pass instead of 16).
__global__ __launch_bounds__(1024) void k_topk(const float* __restrict__ outF,
                                               float* __restrict__ outIds) {
    int b = blockIdx.x, t = threadIdx.x;
    int lane = t & 63;
    __shared__ unsigned hist[256];
    __shared__ unsigned scan[256];
    __shared__ unsigned wsum[4];
    __shared__ unsigned s_pref, s_K, s_iref, s_K2;
    __shared__ unsigned s_cnt;
    __shared__ unsigned long long cand[128];

    const float* src = outF + 800 + b * P_;
    unsigned key[22];
#pragma unroll
    for (int m = 0; m < 21; ++m) key[m] = fkey(src[t + m * 1024]);
    key[21] = (t < 256) ? fkey(src[t + 21504]) : 0u;
    bool has22 = (t < 256);

    if (t == 0) { s_K = 100; s_pref = 0; }

    // ---- 4 MSB-first radix passes on value keys (suffix-sum select) ----
#pragma unroll
    for (int p = 0; p < 4; ++p) {
        int shift = 24 - 8 * p;
        for (int i = t; i < 256; i += 1024) hist[i] = 0;
        __syncthreads();
        unsigned pref = s_pref;
#pragma unroll
        for (int m = 0; m < 22; ++m) {
            if (m < 21 || has22) {
                unsigned u = key[m];
                if (p == 0 || (u >> (shift + 8)) == pref)
                    atomicAdd(&hist[(u >> shift) & 255], 1u);
            }
        }
        __syncthreads();
        unsigned inc = 0, hv = 0;
        if (t < 256) {
            hv = hist[t];
            inc = hv;
#pragma unroll
            for (int off = 1; off < 64; off <<= 1) {
                unsigned u = __shfl_up(inc, off, 64);
                if (lane >= off) inc += u;
            }
            if (lane == 63) wsum[t >> 6] = inc;
        }
        __syncthreads();
        if (t < 256) {
            unsigned base = 0;
#pragma unroll
            for (int w = 0; w < 4; ++w) if (w < (t >> 6)) base += wsum[w];
            unsigned P = base + inc;
            unsigned T4 = wsum[0] + wsum[1] + wsum[2] + wsum[3];
            scan[t] = T4 - P + hv;   // inclusive suffix sum
        }
        __syncthreads();
        unsigned K = s_K;
        if (t < 256) {
            unsigned above = (t == 255) ? 0u : scan[t + 1];
            if (scan[t] >= K && above < K) {
                s_pref = (s_pref << 8) | (unsigned)t;
                s_K = K - above;
            }
        }
        __syncthreads();
    }
    unsigned T = s_pref;
    if (t == 0) { s_K2 = s_K; s_iref = 0; }
    __syncthreads();

    // ---- 2 radix passes on index among ties (prefix-sum select) ----
#pragma unroll
    for (int p = 0; p < 2; ++p) {
        int shift = 8 - 8 * p;
        for (int i = t; i < 256; i += 1024) hist[i] = 0;
        __syncthreads();
        unsigned iref = s_iref;
#pragma unroll
        for (int m = 0; m < 22; ++m) {
            if (m < 21 || has22) {
                unsigned u = key[m];
                unsigned idx = (unsigned)(t + m * 1024);
                if (u == T && (p == 0 || (idx >> 8) == iref))
                    atomicAdd(&hist[(idx >> shift) & 255], 1u);
            }
        }
        __syncthreads();
        unsigned inc = 0;
        if (t < 256) {
            inc = hist[t];
#pragma unroll
            for (int off = 1; off < 64; off <<= 1) {
                unsigned u = __shfl_up(inc, off, 64);
                if (lane >= off) inc += u;
            }
            if (lane == 63) wsum[t >> 6] = inc;
        }
        __syncthreads();
        if (t < 256) {
            unsigned base = 0;
#pragma unroll
            for (int w = 0; w < 4; ++w) if (w < (t >> 6)) base += wsum[w];
            scan[t] = base + inc;    // inclusive prefix sum
        }
        __syncthreads();
        unsigned K2 = s_K2;
        if (t < 256) {
            unsigned below = (t == 0) ? 0u : scan[t - 1];
            if (scan[t] >= K2 && below < K2) {
                s_iref = (s_iref << 8) | (unsigned)t;
                s_K2 = K2 - below;
            }
        }
        __syncthreads();
    }
    unsigned Ti = s_iref;

    if (t == 0) s_cnt = 0;
    if (t < 128) cand[t] = 0ull;
    __syncthreads();
#pragma unroll
    for (int m = 0; m < 22; ++m) {
        if (m < 21 || has22) {
            unsigned u = key[m];
            unsigned idx = (unsigned)(t + m * 1024);
            if (u > T || (u == T && idx <= Ti)) {
                unsigned p = atomicAdd(&s_cnt, 1u);
                if (p < 128)
                    cand[p] = ((unsigned long long)u << 32) | (unsigned long long)(0xFFFFFFFFu - idx);
            }
        }
    }
    __syncthreads();

    for (unsigned k = 2; k <= 128; k <<= 1) {
        for (unsigned j = k >> 1; j > 0; j >>= 1) {
            if (t < 128) {
                unsigned i = t, ixj = i ^ j;
                if (ixj > i) {
                    unsigned long long a = cand[i], c = cand[ixj];
                    bool desc = ((i & k) == 0);
                    if ((a < c) == desc) { cand[i] = c; cand[ixj] = a; }
                }
            }
            __syncthreads();
        }
    }
    if (t < 100) {
        unsigned idx = 0xFFFFFFFFu - (unsigned)(cand[t] & 0xFFFFFFFFull);
        outIds[b * 100 + t] = (float)idx;
    }
}

extern "C" void kernel_launch(void* const* d_in, const int* in_sizes, int n_in,
                              void* d_out, int out_size, void* d_ws, size_t ws_size,
                              hipStream_t stream) {
    const float* x0  = (const float*)d_in[0];
    const float* x1  = (const float*)d_in[1];
    const float* x2  = (const float*)d_in[2];
    const float* x3  = (const float*)d_in[3];
    const float* g1s = (const float*)d_in[4];
    const float* g1b = (const float*)d_in[5];
    const float* W1  = (const float*)d_in[6];
    const float* b1  = (const float*)d_in[7];
    const float* g2s = (const float*)d_in[8];
    const float* g2b = (const float*)d_in[9];
    const float* W2  = (const float*)d_in[10];
    const float* b2  = (const float*)d_in[11];
    float* outF = (float*)d_out;
    float* ws = (float*)d_ws;

    // ws layout (floats)
    float*  ab1   = ws;                     // 16384
    float*  ab2   = ws + 16384;             // 16384
    float*  U     = ws + 32768;             // 43520 (part1/part2)
    float*  part1 = U;
    float*  part2 = U;
    ushort* Whi   = (ushort*)(ws + 76288);  // 65536 ushorts
    ushort* Wlo   = (ushort*)(ws + 109056); // 65536 ushorts

    k_stats1<<<dim3(85, 8), dim3(256), 0, stream>>>(x0, x1, x2, x3, W1, Whi, Wlo, part1);
    k_finalize<<<dim3(256), dim3(64), 0, stream>>>(part1, 256, g1s, g1b, ab1);
    k_gemm<0><<<dim3(256), dim3(512), 0, stream>>>(x0, x1, x2, x3, Whi, Wlo, ab1, b1,
                                                   part2, ab2, W2, b2, outF);
    k_finalize<<<dim3(256), dim3(64), 0, stream>>>(part2, 64, g2s, g2b, ab2);
    k_gemm<2><<<dim3(256), dim3(512), 0, stream>>>(x0, x1, x2, x3, Whi, Wlo, ab1, b1,
                                                   part2, ab2, W2, b2, outF);
    k_topk<<<dim3(8), dim3(1024), 0, stream>>>(outF, outF);
}